// Round 1
// baseline (304.662 us; speedup 1.0000x reference)
//
#include <hip/hip_runtime.h>
#include <hip/hip_bf16.h>

// MultiHeadAttentionEdges: B=2, N=512, H=128, heads=8, dh=16.
// Fused per-(b,i) row block: Ee = E@We (bf16 MFMA, f32 acc), M = Ee*q*k/4,
// logits (exact f32 butterfly), e_out = M@Woe (bf16 MFMA), softmax, att, x_out.

#define NB 2
#define NN 512
#define NHID 128
#define BQ 32   // j-tile rows per iteration (16 iterations)

typedef __bf16 bf16x8 __attribute__((ext_vector_type(8)));
typedef float  f32x4  __attribute__((ext_vector_type(4)));

union U16 { uint4 u; bf16x8 v; };

// ---------------- prep: Qhat/Khat = x@Wq+bq, x@Wk+bk (f32, head-major flat) ----
__global__ __launch_bounds__(128)
void proj_kernel(const float* __restrict__ x,
                 const float* __restrict__ Wq, const float* __restrict__ bq,
                 const float* __restrict__ Wk, const float* __restrict__ bk,
                 float* __restrict__ Qhat, float* __restrict__ Khat)
{
    const int row = blockIdx.x;      // b*512+i
    const int c   = threadIdx.x;     // 0..127
    __shared__ float xs[NHID];
    xs[c] = x[(long)row*NHID + c];
    __syncthreads();
    float q = bq[c], k = bk[c];
    #pragma unroll 8
    for (int kk = 0; kk < NHID; ++kk) {
        const float xv = xs[kk];
        q += xv * Wq[kk*NHID + c];
        k += xv * Wk[kk*NHID + c];
    }
    Qhat[(long)row*NHID + c] = q;
    Khat[(long)row*NHID + c] = k;
}

// ---------------- prep: transposed bf16 weights WeT[c][k]=We[k][c] ------------
__global__ __launch_bounds__(128)
void wcvt_kernel(const float* __restrict__ We, const float* __restrict__ Woe,
                 __bf16* __restrict__ WeT, __bf16* __restrict__ WoeT)
{
    const int cb = blockIdx.x;   // 0..255
    const int k  = threadIdx.x;  // 0..127
    if (cb < NHID) {
        WeT[cb*NHID + k] = (__bf16)We[k*NHID + cb];
    } else {
        const int c = cb - NHID;
        WoeT[c*NHID + k] = (__bf16)Woe[k*NHID + c];
    }
}

// ---------------- main fused kernel: one block per (b,i) ----------------------
__global__ __launch_bounds__(256, 2)
void mha_main(const float* __restrict__ e,
              const float* __restrict__ mask,
              const float* __restrict__ be,
              const float* __restrict__ boe,
              const float* __restrict__ Woh,
              const float* __restrict__ boh,
              const float* __restrict__ Qhat,
              const float* __restrict__ Khat,
              const __bf16* __restrict__ WeT,
              const __bf16* __restrict__ WoeT,
              float* __restrict__ xout,
              float* __restrict__ eout,
              float* __restrict__ sout)
{
    const int i   = blockIdx.x;      // 0..511
    const int b   = blockIdx.y;      // 0..1
    const int tid = threadIdx.x;     // 0..255 (4 waves)
    const int w   = tid >> 6;        // wave 0..3 -> output cols [w*32, w*32+32)
    const int l   = tid & 63;
    const int l15 = l & 15;
    const int lg  = l >> 4;          // 0..3
    const int wcol = w * 32;

    // E tile staged as f32, XOR-swizzled (float-idx ^= (row&7)<<2) -> 2-way max
    __shared__ __align__(16) float  Elds[2][BQ*NHID];   // 32 KB
    __shared__ __align__(16) __bf16 Mlds[BQ*NHID];      // 8 KB, idx ^= (row&7)<<3
    __shared__ float Llog[8][NN];                       // 16 KB logits->probs
    __shared__ float AttP[2][NHID];
    __shared__ float AttF[NHID];

    const long rowbi = (long)b*NN + i;
    const float* Esrc = e    + rowbi*(long)(NN*NHID);
    float*       Edst = eout + rowbi*(long)(NN*NHID);
    const float* Kb   = Khat + (long)b*NN*NHID;

    // per-lane constants + resident B fragments (We, Woe), col = wcol+ct*16+l15
    float qv[2], bev[2], boev[2];
    bf16x8 fWe[2][4], fWoe[2][4];
    #pragma unroll
    for (int ct = 0; ct < 2; ++ct) {
        const int c = wcol + ct*16 + l15;
        qv[ct]   = Qhat[rowbi*NHID + c] * 0.25f;   // fold 1/sqrt(dh)
        bev[ct]  = be[c];
        boev[ct] = boe[c];
        #pragma unroll
        for (int ks = 0; ks < 4; ++ks) {
            const int kb = ks*32 + lg*8;           // B frag: k=(l>>4)*8+i, col=l15
            U16 ua, ub;
            ua.u = *(const uint4*)(WeT  + c*NHID + kb);
            ub.u = *(const uint4*)(WoeT + c*NHID + kb);
            fWe[ct][ks]  = ua.v;
            fWoe[ct][ks] = ub.v;
        }
    }

    float4 rf[4];
    // stage tile 0
    {
        const float4* src = (const float4*)Esrc;
        #pragma unroll
        for (int it = 0; it < 4; ++it) rf[it] = src[it*256 + tid];
        #pragma unroll
        for (int it = 0; it < 4; ++it) {
            const int L = (it*256 + tid)*4;
            const int row = L >> 7, k = L & 127;
            *(float4*)&Elds[0][row*NHID + (k ^ ((row&7)<<2))] = rf[it];
        }
    }

    for (int t = 0; t < 16; ++t) {
        const int cur = t & 1;
        // issue-early prefetch of next tile (consumed at ds_write below)
        if (t < 15) {
            const float4* src = (const float4*)(Esrc + (long)(t+1)*(BQ*NHID));
            #pragma unroll
            for (int it = 0; it < 4; ++it) rf[it] = src[it*256 + tid];
        }
        __syncthreads();   // publish E[cur]; Mlds free (prev GEMM2 done)

        // ---- GEMM1: Ee = E@We, f32 acc; D: col=l15 (=output c), row=lg*4+reg
        f32x4 acc1[2][2] = {};
        #pragma unroll
        for (int ks = 0; ks < 4; ++ks) {
            bf16x8 fa[2];
            #pragma unroll
            for (int rt = 0; rt < 2; ++rt) {
                const int row = rt*16 + l15;
                const int kb  = ks*32 + lg*8;
                const int sw  = (row & 7) << 2;
                const float* bp = &Elds[cur][row*NHID];
                const float4 a0 = *(const float4*)(bp + ((kb    ) ^ sw));
                const float4 a1 = *(const float4*)(bp + ((kb + 4) ^ sw));
                bf16x8 v;
                v[0]=(__bf16)a0.x; v[1]=(__bf16)a0.y; v[2]=(__bf16)a0.z; v[3]=(__bf16)a0.w;
                v[4]=(__bf16)a1.x; v[5]=(__bf16)a1.y; v[6]=(__bf16)a1.z; v[7]=(__bf16)a1.w;
                fa[rt] = v;
            }
            #pragma unroll
            for (int rt = 0; rt < 2; ++rt)
                #pragma unroll
                for (int ct = 0; ct < 2; ++ct)
                    acc1[rt][ct] = __builtin_amdgcn_mfma_f32_16x16x32_bf16(
                        fa[rt], fWe[ct][ks], acc1[rt][ct], 0, 0, 0);
        }

        // ---- elementwise M = (Ee+be)*q*k*0.25 ; exact-f32 logits ; M->LDS bf16
        #pragma unroll
        for (int rt = 0; rt < 2; ++rt) {
            #pragma unroll
            for (int ct = 0; ct < 2; ++ct) {
                const int c = wcol + ct*16 + l15;
                #pragma unroll
                for (int rg = 0; rg < 4; ++rg) {
                    const int jl = rt*16 + lg*4 + rg;
                    const float ee  = acc1[rt][ct][rg] + bev[ct];
                    const float kvv = Kb[(long)(t*BQ + jl)*NHID + c];
                    const float m   = ee * qv[ct] * kvv;
                    Mlds[jl*NHID + (c ^ ((jl&7)<<3))] = (__bf16)m;
                    float s = m;                         // head-sum over 16 cols
                    s += __shfl_xor(s, 1);
                    s += __shfl_xor(s, 2);
                    s += __shfl_xor(s, 4);
                    s += __shfl_xor(s, 8);
                    if (l15 == 0) Llog[w*2 + ct][t*BQ + jl] = s;
                }
            }
        }

        // write-late: commit prefetched tile into the other buffer
        if (t < 15) {
            #pragma unroll
            for (int it = 0; it < 4; ++it) {
                const int L = (it*256 + tid)*4;
                const int row = L >> 7, k = L & 127;
                *(float4*)&Elds[1-cur][row*NHID + (k ^ ((row&7)<<2))] = rf[it];
            }
        }
        __syncthreads();   // publish Mlds + E[next]

        // ---- GEMM2: e_out tile = M@Woe
        f32x4 acc2[2][2] = {};
        #pragma unroll
        for (int ks = 0; ks < 4; ++ks) {
            bf16x8 fa[2];
            #pragma unroll
            for (int rt = 0; rt < 2; ++rt) {
                const int row = rt*16 + l15;
                const int kb  = ks*32 + lg*8;
                U16 u;
                u.u = *(const uint4*)&Mlds[row*NHID + (kb ^ ((row&7)<<3))];
                fa[rt] = u.v;
            }
            #pragma unroll
            for (int rt = 0; rt < 2; ++rt)
                #pragma unroll
                for (int ct = 0; ct < 2; ++ct)
                    acc2[rt][ct] = __builtin_amdgcn_mfma_f32_16x16x32_bf16(
                        fa[rt], fWoe[ct][ks], acc2[rt][ct], 0, 0, 0);
        }
        #pragma unroll
        for (int rt = 0; rt < 2; ++rt)
            #pragma unroll
            for (int ct = 0; ct < 2; ++ct) {
                const int c = wcol + ct*16 + l15;
                #pragma unroll
                for (int rg = 0; rg < 4; ++rg) {
                    const int jl = rt*16 + lg*4 + rg;
                    Edst[(long)(t*BQ + jl)*NHID + c] = acc2[rt][ct][rg] + boev[ct];
                }
            }
    }
    __syncthreads();

    // ---- softmax over j per head; wave w owns heads 2w, 2w+1 ----------------
    const float* mrow = mask + rowbi*NN;
    #pragma unroll
    for (int hh = 0; hh < 2; ++hh) {
        const int h = w*2 + hh;
        float vb[8];
        float mx = -1e30f;
        #pragma unroll
        for (int q = 0; q < 8; ++q) {
            const int j = q*64 + l;
            const float v = Llog[h][j] + mrow[j];
            vb[q] = v; mx = fmaxf(mx, v);
        }
        #pragma unroll
        for (int mm = 1; mm < 64; mm <<= 1) mx = fmaxf(mx, __shfl_xor(mx, mm));
        float sum = 0.f;
        #pragma unroll
        for (int q = 0; q < 8; ++q) { vb[q] = __expf(vb[q] - mx); sum += vb[q]; }
        #pragma unroll
        for (int mm = 1; mm < 64; mm <<= 1) sum += __shfl_xor(sum, mm);
        const float inv = 1.f / sum;
        float* srow = sout + ((long)(b*8 + h)*NN + i)*NN;
        #pragma unroll
        for (int q = 0; q < 8; ++q) {
            const int j = q*64 + l;
            const float p = vb[q]*inv;
            Llog[h][j] = p;
            srow[j] = p;
        }
    }
    __syncthreads();

    // ---- att[c] = sum_j probs[c>>4][j] * Khat[b][j][c]  (V = K) -------------
    {
        const int half = tid >> 7;      // split j-range across thread halves
        const int c = tid & 127;
        const int h = c >> 4;
        float a = 0.f;
        const float* kp = Kb + (long)(half*256)*NHID + c;
        const float* pp = &Llog[h][half*256];
        #pragma unroll 4
        for (int j = 0; j < 256; ++j) a += pp[j] * kp[(long)j*NHID];
        AttP[half][c] = a;
    }
    __syncthreads();
    if (tid < NHID) AttF[tid] = AttP[0][tid] + AttP[1][tid];
    __syncthreads();

    // ---- x_out row = att@Woh + boh ------------------------------------------
    if (tid < NHID) {
        const int c = tid;
        float acc = boh[c];
        #pragma unroll 8
        for (int k = 0; k < NHID; ++k) acc += AttF[k] * Woh[k*NHID + c];
        xout[rowbi*NHID + c] = acc;
    }
}

extern "C" void kernel_launch(void* const* d_in, const int* in_sizes, int n_in,
                              void* d_out, int out_size, void* d_ws, size_t ws_size,
                              hipStream_t stream) {
    const float* x    = (const float*)d_in[0];
    const float* e    = (const float*)d_in[1];
    const float* mask = (const float*)d_in[2];
    const float* Wq   = (const float*)d_in[3];
    const float* bq   = (const float*)d_in[4];
    const float* Wk   = (const float*)d_in[5];
    const float* bk   = (const float*)d_in[6];
    const float* We   = (const float*)d_in[7];
    const float* be   = (const float*)d_in[8];
    const float* Woh  = (const float*)d_in[9];
    const float* boh  = (const float*)d_in[10];
    const float* Woe  = (const float*)d_in[11];
    const float* boe  = (const float*)d_in[12];

    float*  Qhat = (float*)d_ws;                 // 512 KB
    float*  Khat = Qhat + NB*NN*NHID;            // 512 KB
    __bf16* WeT  = (__bf16*)(Khat + NB*NN*NHID); // 32 KB
    __bf16* WoeT = WeT + NHID*NHID;              // 32 KB

    float* xout = (float*)d_out;                     // [2,512,128]
    float* eout = xout + (long)NB*NN*NHID;           // [2,512,512,128]
    float* sout = eout + (long)NB*NN*NN*NHID;        // [2,8,512,512]

    proj_kernel<<<dim3(NB*NN), 128, 0, stream>>>(x, Wq, bq, Wk, bk, Qhat, Khat);
    wcvt_kernel<<<dim3(2*NHID), 128, 0, stream>>>(We, Woe, WeT, WoeT);
    mha_main<<<dim3(NN, NB), 256, 0, stream>>>(e, mask, be, boe, Woh, boh,
                                               Qhat, Khat, WeT, WoeT,
                                               xout, eout, sout);
}